// Round 4
// baseline (231.610 us; speedup 1.0000x reference)
//
#include <hip/hip_runtime.h>
#include <hip/hip_bf16.h>
#include <math.h>

#define BB 32
#define TT 4096
#define NN 11
#define FF 16
#define HH 32
#define LN_EPS 1e-5f
#define TOTAL_ROWS (BB * TT * NN)                   // 1,441,792
#define ROWS_PER_BLOCK 256
#define NBLOCKS (TOTAL_ROWS / ROWS_PER_BLOCK)       // 5632 exact
#define BLOCKS_PER_BATCH (TT * NN / ROWS_PER_BLOCK) // 176 exact -> lab uniform per block

typedef __attribute__((ext_vector_type(8))) short short8;  // 8 bf16 = 4 VGPRs
typedef __attribute__((ext_vector_type(4))) float f32x4;

union Frag { unsigned u[4]; uint4 u4; short8 v; };

__device__ __forceinline__ unsigned pack2_bf16(float a, float b) {
    __hip_bfloat162 p = __float22bfloat162_rn(make_float2(a, b));
    union { __hip_bfloat162 h; unsigned u; } cvt; cvt.h = p; return cvt.u;
}

// tanh-form GELU via sigmoid; max dev from exact-erf GELU ~3e-3
__device__ __forceinline__ float fast_gelu(float v) {
    const float v2 = v * v;
    const float c  = fmaf(0.044715f, v2, 1.0f);
    const float t  = v * c * 1.5957691216057308f;
    const float e  = __expf(-t);
    return v * __builtin_amdgcn_rcpf(1.0f + e);
}

__global__ __launch_bounds__(256) void fused_proj_mlp_t(
    const float* __restrict__ x,        // [B,T,N,F]
    const int*   __restrict__ lab_idx,  // [B]
    const float* __restrict__ proj,     // [L,N,N]
    const float* __restrict__ bias,     // [L,1,N,F]
    const float* __restrict__ w1,       // [F,H]
    const float* __restrict__ b1,       // [H]
    const float* __restrict__ ln_g,     // [H]
    const float* __restrict__ ln_b,     // [H]
    const float* __restrict__ w2,       // [H,F]
    const float* __restrict__ b2,       // [F]
    float*       __restrict__ out)      // [B,T,N,F]
{
    // per-wave o staging: 64 rows x 8 dwords (bf16 pairs), stride 12 dwords.
    // Written and read by the SAME wave -> no __syncthreads anywhere.
    __shared__ unsigned o_st[4][64][12];

    const int tid  = threadIdx.x;
    const int wv   = tid >> 6;
    const int lane = tid & 63;
    const int q    = lane >> 4;    // quad 0..3
    const int c    = lane & 15;    // column / token-within-tile

    const int row        = blockIdx.x * ROWS_PER_BLOCK + tid;
    const unsigned token = (unsigned)row / 11u;
    const int m          = row - (int)(token * 11u);
    const int lab        = lab_idx[blockIdx.x / BLOCKS_PER_BATCH];

    // ---------- weight fragments as A-operands (transposed GEMMs) ----------
    // A1 chunk0: A[m=c][k=8q+j] = w1[k][c]      (H rows 0..15)   zero for q>=2 (K=16 pad)
    // A1 chunk1: A[m=c][k=8q+j] = w1[k][16+c]   (H rows 16..31)  zero for q>=2
    // A2:        A[m=c][k=8q+j] = w2[k][c]      (K=32, all valid)
    Frag a1c0, a1c1, a2f;
    #pragma unroll
    for (int d = 0; d < 4; ++d) {
        const int k0 = 8 * q + 2 * d;
        float wa0 = 0.f, wa1 = 0.f, wb0 = 0.f, wb1 = 0.f;
        if (q < 2) {
            wa0 = w1[k0 * HH + c];       wa1 = w1[(k0 + 1) * HH + c];
            wb0 = w1[k0 * HH + 16 + c];  wb1 = w1[(k0 + 1) * HH + 16 + c];
        }
        a1c0.u[d] = pack2_bf16(wa0, wa1);
        a1c1.u[d] = pack2_bf16(wb0, wb1);
        a2f.u[d]  = pack2_bf16(w2[k0 * FF + c], w2[(k0 + 1) * FF + c]);
    }

    // per-lane row constants: H index = chunk*16 + q*4 + i ; f index = q*4 + i
    float4 b1v0 = *reinterpret_cast<const float4*>(b1 + 4 * q);
    float4 b1v1 = *reinterpret_cast<const float4*>(b1 + 16 + 4 * q);
    float4 b2v  = *reinterpret_cast<const float4*>(b2 + 4 * q);
    float4 g0   = *reinterpret_cast<const float4*>(ln_g + 4 * q);
    float4 g1   = *reinterpret_cast<const float4*>(ln_g + 16 + 4 * q);
    float4 e0   = *reinterpret_cast<const float4*>(ln_b + 4 * q);
    float4 e1   = *reinterpret_cast<const float4*>(ln_b + 16 + 4 * q);
    float g0a[4] = {g0.x, g0.y, g0.z, g0.w}, g1a[4] = {g1.x, g1.y, g1.z, g1.w};
    float e0a[4] = {e0.x, e0.y, e0.z, e0.w}, e1a[4] = {e1.x, e1.y, e1.z, e1.w};
    float b1a0[4] = {b1v0.x, b1v0.y, b1v0.z, b1v0.w};
    float b1a1[4] = {b1v1.x, b1v1.y, b1v1.z, b1v1.w};
    float b2a[4]  = {b2v.x, b2v.y, b2v.z, b2v.w};

    // ---------- fp32 projection (exact) ----------
    const float4* xp4 = reinterpret_cast<const float4*>(x) + (size_t)token * (NN * FF / 4);
    const float*  Wp  = proj + (size_t)lab * (NN * NN) + m;
    const float4* bp4 = reinterpret_cast<const float4*>(bias) + (size_t)lab * (NN * FF / 4) + m * (FF / 4);

    float o[FF];
    #pragma unroll
    for (int f4 = 0; f4 < FF / 4; ++f4) {
        float4 v = bp4[f4];
        o[f4*4+0] = v.x; o[f4*4+1] = v.y; o[f4*4+2] = v.z; o[f4*4+3] = v.w;
    }
    #pragma unroll
    for (int n = 0; n < NN; ++n) {
        const float wnm = Wp[n * NN];
        #pragma unroll
        for (int f4 = 0; f4 < FF / 4; ++f4) {
            float4 v = xp4[n * (FF / 4) + f4];
            o[f4*4+0] = fmaf(v.x, wnm, o[f4*4+0]);
            o[f4*4+1] = fmaf(v.y, wnm, o[f4*4+1]);
            o[f4*4+2] = fmaf(v.z, wnm, o[f4*4+2]);
            o[f4*4+3] = fmaf(v.w, wnm, o[f4*4+3]);
        }
    }

    // pack o -> bf16 pairs, stage to per-wave LDS (row = lane)
    {
        unsigned p[8];
        #pragma unroll
        for (int d = 0; d < 8; ++d) p[d] = pack2_bf16(o[2*d], o[2*d+1]);
        uint4* dst = reinterpret_cast<uint4*>(&o_st[wv][lane][0]);
        dst[0] = make_uint4(p[0], p[1], p[2], p[3]);
        dst[1] = make_uint4(p[4], p[5], p[6], p[7]);
    }
    // no barrier: same-wave producer/consumer, lgkmcnt ordering suffices

    const int rowbase = blockIdx.x * ROWS_PER_BLOCK + wv * 64;
    const int srcA = (q & 1) * 32 + c;   // B2 source lanes
    const int srcB = srcA + 16;

    #pragma unroll
    for (int tt = 0; tt < 4; ++tt) {
        // ---- GEMM1 (transposed): B1[k=f=8q+j][n=c] = o[token=tile row c][f]
        // q>=2 reads f0..7 again (finite values) x zero A-frag -> contributes 0.
        Frag B1;
        B1.u4 = *reinterpret_cast<const uint4*>(&o_st[wv][tt * 16 + c][(q & 1) * 4]);

        f32x4 accA = { b1a0[0], b1a0[1], b1a0[2], b1a0[3] };  // h^T rows 0..15
        f32x4 accB = { b1a1[0], b1a1[1], b1a1[2], b1a1[3] };  // h^T rows 16..31
        accA = __builtin_amdgcn_mfma_f32_16x16x32_bf16(a1c0.v, B1.v, accA, 0, 0, 0);
        accB = __builtin_amdgcn_mfma_f32_16x16x32_bf16(a1c1.v, B1.v, accB, 0, 0, 0);

        // ---- LayerNorm over H=32: lane holds 8 values of token c
        float s = 0.f, ss = 0.f;
        #pragma unroll
        for (int i = 0; i < 4; ++i) {
            s += accA[i] + accB[i];
            ss = fmaf(accA[i], accA[i], ss);
            ss = fmaf(accB[i], accB[i], ss);
        }
        s  += __shfl_xor(s, 16, 64);  s  += __shfl_xor(s, 32, 64);
        ss += __shfl_xor(ss, 16, 64); ss += __shfl_xor(ss, 32, 64);
        const float mu   = s * (1.f / HH);
        const float var  = ss * (1.f / HH) - mu * mu;
        const float rstd = rsqrtf(var + LN_EPS);
        const float nb   = -mu * rstd;

        // ---- affine + GELU, pack per chunk
        float ga[4], gb[4];
        #pragma unroll
        for (int i = 0; i < 4; ++i) {
            ga[i] = fast_gelu(fmaf(fmaf(accA[i], rstd, nb), g0a[i], e0a[i]));
            gb[i] = fast_gelu(fmaf(fmaf(accB[i], rstd, nb), g1a[i], e1a[i]));
        }
        const unsigned c0d0 = pack2_bf16(ga[0], ga[1]);
        const unsigned c0d1 = pack2_bf16(ga[2], ga[3]);
        const unsigned c1d0 = pack2_bf16(gb[0], gb[1]);
        const unsigned c1d1 = pack2_bf16(gb[2], gb[3]);

        // ---- register transpose to B2-frag: B2[k=H=8q+j][n=c]
        // k=8q+j : chunk = q>>1, source quad r = 2(q&1) (+1 for j>=4), src lane = r*16+c
        Frag B2;
        {
            unsigned lo, hi;
            lo = __shfl((int)c0d0, srcA, 64); hi = __shfl((int)c1d0, srcA, 64);
            B2.u[0] = (q < 2) ? lo : hi;
            lo = __shfl((int)c0d1, srcA, 64); hi = __shfl((int)c1d1, srcA, 64);
            B2.u[1] = (q < 2) ? lo : hi;
            lo = __shfl((int)c0d0, srcB, 64); hi = __shfl((int)c1d0, srcB, 64);
            B2.u[2] = (q < 2) ? lo : hi;
            lo = __shfl((int)c0d1, srcB, 64); hi = __shfl((int)c1d1, srcB, 64);
            B2.u[3] = (q < 2) ? lo : hi;
        }

        // ---- GEMM2 (transposed, K=32): out^T[f=q*4+i][token=c]
        f32x4 acc2 = { b2a[0], b2a[1], b2a[2], b2a[3] };
        acc2 = __builtin_amdgcn_mfma_f32_16x16x32_bf16(a2f.v, B2.v, acc2, 0, 0, 0);

        // ---- contiguous float4 store: out[row = rowbase+tt*16+c][f = q*4 .. q*4+3]
        float4* dst = reinterpret_cast<float4*>(out + (size_t)(rowbase + tt * 16 + c) * FF + 4 * q);
        *dst = make_float4(acc2[0], acc2[1], acc2[2], acc2[3]);
    }
}

extern "C" void kernel_launch(void* const* d_in, const int* in_sizes, int n_in,
                              void* d_out, int out_size, void* d_ws, size_t ws_size,
                              hipStream_t stream) {
    const float* x       = (const float*)d_in[0];
    const int*   lab_idx = (const int*)  d_in[1];
    const float* proj    = (const float*)d_in[2];
    const float* bias    = (const float*)d_in[3];
    const float* w1      = (const float*)d_in[4];
    const float* b1      = (const float*)d_in[5];
    const float* ln_g    = (const float*)d_in[6];
    const float* ln_b    = (const float*)d_in[7];
    const float* w2      = (const float*)d_in[8];
    const float* b2      = (const float*)d_in[9];
    float* out = (float*)d_out;

    fused_proj_mlp_t<<<NBLOCKS, 256, 0, stream>>>(
        x, lab_idx, proj, bias, w1, b1, ln_g, ln_b, w2, b2, out);
}

// Round 5
// 200.297 us; speedup vs baseline: 1.1563x; 1.1563x over previous
//
#include <hip/hip_runtime.h>
#include <hip/hip_bf16.h>
#include <math.h>

#define BB 32
#define TT 4096
#define NN 11
#define FF 16
#define HH 32
#define LN_EPS 1e-5f

// Block: 256 threads = 64 tokens x 4 f-chunks. 2048 blocks total.
// Wave wv owns tokens [16wv,16wv+16) -> LDS rows [176wv,176wv+176) -> 11 MFMA tiles.
#define TOKENS_PER_BLOCK 64
#define NBLOCKS (BB * TT / TOKENS_PER_BLOCK)          // 2048
#define BLOCKS_PER_BATCH (TT / TOKENS_PER_BLOCK)      // 64 (exact) -> lab uniform
#define ROW_STRIDE_B 48                               // 24 bf16; 16B-aligned, odd-x16B -> few conflicts

typedef __attribute__((ext_vector_type(8))) short short8;  // 8 bf16 = 4 VGPRs
typedef __attribute__((ext_vector_type(4))) float f32x4;

union Frag { unsigned u[4]; uint4 u4; short8 v; };

__device__ __forceinline__ unsigned pack2_bf16(float a, float b) {
    __hip_bfloat162 p = __float22bfloat162_rn(make_float2(a, b));
    union { __hip_bfloat162 h; unsigned u; } cvt; cvt.h = p; return cvt.u;
}

// tanh-form GELU via sigmoid; max dev from exact-erf GELU ~3e-3
__device__ __forceinline__ float fast_gelu(float v) {
    const float v2 = v * v;
    const float c  = fmaf(0.044715f, v2, 1.0f);
    const float t  = v * c * 1.5957691216057308f;
    const float e  = __expf(-t);
    return v * __builtin_amdgcn_rcpf(1.0f + e);
}

__global__ __launch_bounds__(256) void fused_v5(
    const float* __restrict__ x,        // [B,T,N,F]
    const int*   __restrict__ lab_idx,  // [B]
    const float* __restrict__ proj,     // [L,N,N]
    const float* __restrict__ bias,     // [L,1,N,F]
    const float* __restrict__ w1,       // [F,H]
    const float* __restrict__ b1,       // [H]
    const float* __restrict__ ln_g,     // [H]
    const float* __restrict__ ln_b,     // [H]
    const float* __restrict__ w2,       // [H,F]
    const float* __restrict__ b2,       // [F]
    float*       __restrict__ out)      // [B,T,N,F]
{
    // 704 rows x 48 B = 33792 B. Row r = tl*11 + m (token-major, matches out order).
    __shared__ __align__(16) unsigned char o_st[704 * ROW_STRIDE_B];

    const int tid  = threadIdx.x;
    const int wv   = tid >> 6;
    const int lane = tid & 63;
    const int q    = lane >> 4;
    const int c    = lane & 15;
    const int tl   = tid >> 2;          // token-local 0..63
    const int f4   = tid & 3;           // f-chunk 0..3

    const int token = blockIdx.x * TOKENS_PER_BLOCK + tl;
    const int lab   = lab_idx[blockIdx.x / BLOCKS_PER_BATCH];   // block-uniform -> SGPR

    // ---------- weight fragments as A-operands (verified in R4) ----------
    Frag a1c0, a1c1, a2f;
    #pragma unroll
    for (int d = 0; d < 4; ++d) {
        const int k0 = 8 * q + 2 * d;
        float wa0 = 0.f, wa1 = 0.f, wb0 = 0.f, wb1 = 0.f;
        if (q < 2) {
            wa0 = w1[k0 * HH + c];       wa1 = w1[(k0 + 1) * HH + c];
            wb0 = w1[k0 * HH + 16 + c];  wb1 = w1[(k0 + 1) * HH + 16 + c];
        }
        a1c0.u[d] = pack2_bf16(wa0, wa1);
        a1c1.u[d] = pack2_bf16(wb0, wb1);
        a2f.u[d]  = pack2_bf16(w2[k0 * FF + c], w2[(k0 + 1) * FF + c]);
    }

    float4 b1v0 = *reinterpret_cast<const float4*>(b1 + 4 * q);
    float4 b1v1 = *reinterpret_cast<const float4*>(b1 + 16 + 4 * q);
    float4 b2v  = *reinterpret_cast<const float4*>(b2 + 4 * q);
    float4 g0   = *reinterpret_cast<const float4*>(ln_g + 4 * q);
    float4 g1   = *reinterpret_cast<const float4*>(ln_g + 16 + 4 * q);
    float4 e0   = *reinterpret_cast<const float4*>(ln_b + 4 * q);
    float4 e1   = *reinterpret_cast<const float4*>(ln_b + 16 + 4 * q);
    float g0a[4] = {g0.x, g0.y, g0.z, g0.w}, g1a[4] = {g1.x, g1.y, g1.z, g1.w};
    float e0a[4] = {e0.x, e0.y, e0.z, e0.w}, e1a[4] = {e1.x, e1.y, e1.z, e1.w};
    float b1a0[4] = {b1v0.x, b1v0.y, b1v0.z, b1v0.w};
    float b1a1[4] = {b1v1.x, b1v1.y, b1v1.z, b1v1.w};
    float b2a[4]  = {b2v.x, b2v.y, b2v.z, b2v.w};

    // ---------- projection: thread (token, f4) computes o[m][0..3] for all m ----------
    // x read exactly once per element (disjoint across threads), weights from SGPRs.
    const float4* xb = reinterpret_cast<const float4*>(x)    + (size_t)token * (NN * FF / 4) + f4;
    const float4* bb = reinterpret_cast<const float4*>(bias) + (size_t)lab   * (NN * FF / 4) + f4;
    const float*  Wl = proj + (size_t)lab * (NN * NN);       // uniform base -> s_load

    float o[NN][4];
    #pragma unroll
    for (int m = 0; m < NN; ++m) {
        float4 bv = bb[4 * m];
        o[m][0] = bv.x; o[m][1] = bv.y; o[m][2] = bv.z; o[m][3] = bv.w;
    }
    #pragma unroll
    for (int n = 0; n < NN; ++n) {
        float4 xv = xb[4 * n];
        #pragma unroll
        for (int m = 0; m < NN; ++m) {
            const float wm = Wl[n * NN + m];   // uniform -> SGPR operand
            o[m][0] = fmaf(xv.x, wm, o[m][0]);
            o[m][1] = fmaf(xv.y, wm, o[m][1]);
            o[m][2] = fmaf(xv.z, wm, o[m][2]);
            o[m][3] = fmaf(xv.w, wm, o[m][3]);
        }
    }

    // ---------- stage o -> LDS bf16, row r = tl*11+m, this wave's own region ----------
    #pragma unroll
    for (int m = 0; m < NN; ++m) {
        uint2 p;
        p.x = pack2_bf16(o[m][0], o[m][1]);
        p.y = pack2_bf16(o[m][2], o[m][3]);
        *reinterpret_cast<uint2*>(&o_st[(tl * NN + m) * ROW_STRIDE_B + f4 * 8]) = p;
    }
    // no __syncthreads: rows [176wv,176wv+176) were written by this wave's own lanes;
    // same-wave LDS ops are pipe-ordered.

    const size_t outrow0 = (size_t)blockIdx.x * (TOKENS_PER_BLOCK * NN) + wv * 176;
    const int srcA = (q & 1) * 32 + c;
    const int srcB = srcA + 16;

    #pragma unroll
    for (int t = 0; t < NN; ++t) {
        // ---- GEMM1 (transposed): B1[k=f=8q+j][col=c] = o_bf16[row 176wv+16t+c][f]
        Frag B1;
        B1.u4 = *reinterpret_cast<const uint4*>(
            &o_st[(176 * wv + 16 * t + c) * ROW_STRIDE_B + (q & 1) * 16]);

        f32x4 accA = { b1a0[0], b1a0[1], b1a0[2], b1a0[3] };
        f32x4 accB = { b1a1[0], b1a1[1], b1a1[2], b1a1[3] };
        accA = __builtin_amdgcn_mfma_f32_16x16x32_bf16(a1c0.v, B1.v, accA, 0, 0, 0);
        accB = __builtin_amdgcn_mfma_f32_16x16x32_bf16(a1c1.v, B1.v, accB, 0, 0, 0);

        // ---- LayerNorm over H=32 (column c's values live in lanes c, c+16, c+32, c+48)
        float s = 0.f, ss = 0.f;
        #pragma unroll
        for (int i = 0; i < 4; ++i) {
            s += accA[i] + accB[i];
            ss = fmaf(accA[i], accA[i], ss);
            ss = fmaf(accB[i], accB[i], ss);
        }
        s  += __shfl_xor(s, 16, 64);  s  += __shfl_xor(s, 32, 64);
        ss += __shfl_xor(ss, 16, 64); ss += __shfl_xor(ss, 32, 64);
        const float mu   = s * (1.f / HH);
        const float var  = ss * (1.f / HH) - mu * mu;
        const float rstd = rsqrtf(var + LN_EPS);
        const float nb   = -mu * rstd;

        // ---- affine + GELU
        float ga[4], gb[4];
        #pragma unroll
        for (int i = 0; i < 4; ++i) {
            ga[i] = fast_gelu(fmaf(fmaf(accA[i], rstd, nb), g0a[i], e0a[i]));
            gb[i] = fast_gelu(fmaf(fmaf(accB[i], rstd, nb), g1a[i], e1a[i]));
        }
        const unsigned c0d0 = pack2_bf16(ga[0], ga[1]);
        const unsigned c0d1 = pack2_bf16(ga[2], ga[3]);
        const unsigned c1d0 = pack2_bf16(gb[0], gb[1]);
        const unsigned c1d1 = pack2_bf16(gb[2], gb[3]);

        // ---- register transpose to B2-frag (verified in R4)
        Frag B2;
        {
            unsigned lo, hi;
            lo = __shfl((int)c0d0, srcA, 64); hi = __shfl((int)c1d0, srcA, 64);
            B2.u[0] = (q < 2) ? lo : hi;
            lo = __shfl((int)c0d1, srcA, 64); hi = __shfl((int)c1d1, srcA, 64);
            B2.u[1] = (q < 2) ? lo : hi;
            lo = __shfl((int)c0d0, srcB, 64); hi = __shfl((int)c1d0, srcB, 64);
            B2.u[2] = (q < 2) ? lo : hi;
            lo = __shfl((int)c0d1, srcB, 64); hi = __shfl((int)c1d1, srcB, 64);
            B2.u[3] = (q < 2) ? lo : hi;
        }

        // ---- GEMM2 (transposed, K=32): out^T[f=4q+i][col=c]
        f32x4 acc2 = { b2a[0], b2a[1], b2a[2], b2a[3] };
        acc2 = __builtin_amdgcn_mfma_f32_16x16x32_bf16(a2f.v, B2.v, acc2, 0, 0, 0);

        // ---- contiguous float4 store: row = outrow0 + 16t + c, f = 4q..4q+3
        float4* dst = reinterpret_cast<float4*>(out + (outrow0 + 16 * t + c) * FF + 4 * q);
        *dst = make_float4(acc2[0], acc2[1], acc2[2], acc2[3]);
    }
}

extern "C" void kernel_launch(void* const* d_in, const int* in_sizes, int n_in,
                              void* d_out, int out_size, void* d_ws, size_t ws_size,
                              hipStream_t stream) {
    const float* x       = (const float*)d_in[0];
    const int*   lab_idx = (const int*)  d_in[1];
    const float* proj    = (const float*)d_in[2];
    const float* bias    = (const float*)d_in[3];
    const float* w1      = (const float*)d_in[4];
    const float* b1      = (const float*)d_in[5];
    const float* ln_g    = (const float*)d_in[6];
    const float* ln_b    = (const float*)d_in[7];
    const float* w2      = (const float*)d_in[8];
    const float* b2      = (const float*)d_in[9];
    float* out = (float*)d_out;

    fused_v5<<<NBLOCKS, 256, 0, stream>>>(
        x, lab_idx, proj, bias, w1, b1, ln_g, ln_b, w2, b2, out);
}